// Round 5
// baseline (546.910 us; speedup 1.0000x reference)
//
#include <hip/hip_runtime.h>
#include <hip/hip_bf16.h>

#define B_ 64
#define T_ 200
#define E_ 512
#define H_ 8
#define D_ 64

static constexpr float SCALE = 0.044194173824159216f;  // 512^-0.5

typedef __attribute__((ext_vector_type(8))) short bf16x8;
typedef __attribute__((ext_vector_type(4))) float f32x4;

static __device__ inline short f2bf(float f) {
    __hip_bfloat16 h = __float2bfloat16(f);
    return *(short*)&h;
}

// ---------------- fused prep: all weight transposes + memory convert ------------
// mode 0: (K,N) f32 -> (N,K) bf16.  mode 1: (H,K,D) f32 -> (N=h*64+d, K) bf16.
// mode 2: straight f32 -> bf16 convert.
struct PrepJobs {
    const float* src[11];
    __hip_bfloat16* dst[11];
    int N[11], K[11], mode[11];
    int prefix[12];
};

__global__ __launch_bounds__(256) void prep_kernel(PrepJobs jb) {
    int total = jb.prefix[11];
    int stride = gridDim.x * blockDim.x;
    for (int i = blockIdx.x * blockDim.x + threadIdx.x; i < total; i += stride) {
        int j = 0;
        while (i >= jb.prefix[j + 1]) ++j;
        int local = i - jb.prefix[j];
        const float* s = jb.src[j];
        float v;
        if (jb.mode[j] == 2) {
            v = s[local];
        } else {
            int K = jb.K[j];
            int n = local / K, k = local - n * K;
            if (jb.mode[j] == 0) {
                v = s[(size_t)k * jb.N[j] + n];
            } else {
                int h = n >> 6, d = n & 63;
                v = s[((size_t)h * K + k) * 64 + d];
            }
        }
        jb.dst[j][local] = __float2bfloat16(v);
    }
}

// ---------------- LayerNorm over E=512 -> bf16 out, one block per row ----------------
__global__ __launch_bounds__(256) void ln_kernel(const float* __restrict__ x,
                                                 const float* __restrict__ g,
                                                 const float* __restrict__ bta,
                                                 __hip_bfloat16* __restrict__ out) {
    __shared__ float red[4];
    int row = blockIdx.x;
    const float* xr = x + (size_t)row * E_;
    int tid = threadIdx.x;
    float v0 = xr[tid], v1 = xr[tid + 256];
    float s = v0 + v1;
    for (int off = 32; off; off >>= 1) s += __shfl_down(s, off, 64);
    if ((tid & 63) == 0) red[tid >> 6] = s;
    __syncthreads();
    float mu = (red[0] + red[1] + red[2] + red[3]) * (1.0f / E_);
    __syncthreads();
    float d0 = v0 - mu, d1 = v1 - mu;
    float sq = d0 * d0 + d1 * d1;
    for (int off = 32; off; off >>= 1) sq += __shfl_down(sq, off, 64);
    if ((tid & 63) == 0) red[tid >> 6] = sq;
    __syncthreads();
    float var = (red[0] + red[1] + red[2] + red[3]) * (1.0f / E_);
    float r = rsqrtf(var + 1e-5f);
    out[(size_t)row * E_ + tid] = __float2bfloat16(g[tid] * d0 * r + bta[tid]);
    out[(size_t)row * E_ + tid + 256] =
        __float2bfloat16(g[tid + 256] * d1 * r + bta[tid + 256]);
}

// ---------------- MFMA bf16 GEMM: C(MxN) = A(MxK) * BT(NxK)^T + epilogue --------
// 128x128 tile, BK=32, 256 threads (4 waves, each 64x64 via 4x4 of 16x16x32 MFMA).
// LDS in fragment-major layout [mt 8][g 4][l 16][j 8] -> conflict-free staging+frag reads.
// MSK: 0=none, 1=row-mask all cols, 2=row-mask cols<1024 only.  RELU: relu.
// OM: 0 = f32 MxN, 1 = bf16 (B,H,T,D) qkv layout (seg=(col>>9)*SEGMUL), 2 = bf16 MxN.
// RES: add resid[row*N+col] (f32).  BIAS: add bias[col] (f32).
template <int MSK, int RELU, int OM, int RES, int BIAS, int SEGMUL = 1>
__global__ __launch_bounds__(256) void mgemm_kernel(
    const short* __restrict__ A, const short* __restrict__ BT,
    const float* __restrict__ bias, const int* __restrict__ rmask,
    const float* __restrict__ resid, void* __restrict__ Cv,
    int M, int N, int K) {
    __shared__ short As[128 * 32];
    __shared__ short Bs[128 * 32];
    int tid = threadIdx.x;
    int wave = tid >> 6, lane = tid & 63;
    int qq = lane >> 4, l15 = lane & 15;
    int m0 = blockIdx.y * 128, n0 = blockIdx.x * 128;
    int wmt = (wave & 1) * 4, wnt = (wave >> 1) * 4;   // tile-of-16 indices

    int sr = tid >> 2;            // staging row 0..63
    int sg = tid & 3;             // staging k-chunk 0..3
    f32x4 acc[4][4] = {};

    for (int k0 = 0; k0 < K; k0 += 32) {
        #pragma unroll
        for (int half = 0; half < 2; ++half) {
            int r = sr + half * 64;
            int sidx = (((r >> 4) * 4 + sg) * 16 + (r & 15)) * 8;
            *(bf16x8*)(&As[sidx]) =
                *(const bf16x8*)(&A[(size_t)(m0 + r) * K + k0 + sg * 8]);
            *(bf16x8*)(&Bs[sidx]) =
                *(const bf16x8*)(&BT[(size_t)(n0 + r) * K + k0 + sg * 8]);
        }
        __syncthreads();
        bf16x8 af[4], bfr[4];
        #pragma unroll
        for (int i = 0; i < 4; ++i)
            af[i] = *(bf16x8*)(&As[(((wmt + i) * 4 + qq) * 16 + l15) * 8]);
        #pragma unroll
        for (int j = 0; j < 4; ++j)
            bfr[j] = *(bf16x8*)(&Bs[(((wnt + j) * 4 + qq) * 16 + l15) * 8]);
        #pragma unroll
        for (int i = 0; i < 4; ++i)
            #pragma unroll
            for (int j = 0; j < 4; ++j)
                acc[i][j] = __builtin_amdgcn_mfma_f32_16x16x32_bf16(
                    af[i], bfr[j], acc[i][j], 0, 0, 0);
        __syncthreads();
    }

    #pragma unroll
    for (int i = 0; i < 4; ++i) {
        #pragma unroll
        for (int r = 0; r < 4; ++r) {
            int row = m0 + (wmt + i) * 16 + qq * 4 + r;
            float mval = 1.0f;
            if (MSK) mval = (rmask[row] != 0) ? 1.0f : 0.0f;
            #pragma unroll
            for (int j = 0; j < 4; ++j) {
                int col = n0 + (wnt + j) * 16 + l15;
                float val = acc[i][j][r];
                if (BIAS) val += bias[col];
                if (MSK == 1) val *= mval;
                if (MSK == 2 && col < 1024) val *= mval;
                if (RELU) val = fmaxf(val, 0.0f);
                if (RES) val += resid[(size_t)row * N + col];
                if (OM == 0) {
                    ((float*)Cv)[(size_t)row * N + col] = val;
                } else if (OM == 1) {
                    int b_ = row / T_, t = row % T_;
                    int seg = (col >> 9) * SEGMUL;
                    int h = (col >> 6) & 7, d = col & 63;
                    ((__hip_bfloat16*)Cv)[((((size_t)seg * B_ * H_) +
                        (size_t)b_ * H_ + h) * T_ + t) * D_ + d] = __float2bfloat16(val);
                } else {
                    ((__hip_bfloat16*)Cv)[(size_t)row * N + col] =
                        __float2bfloat16(val);
                }
            }
        }
    }
}

// ---------------- MFMA causal attention: one block per (b,h), bf16 in/out -------
// q,k,v: (B*H, T, D) bf16.  o: (B,T,E) bf16, e = h*64+d.
#define NQT 13
__global__ __launch_bounds__(256) void fattn_kernel(const __hip_bfloat16* __restrict__ q,
                                                    const __hip_bfloat16* __restrict__ k,
                                                    const __hip_bfloat16* __restrict__ v,
                                                    __hip_bfloat16* __restrict__ o) {
    // Kf: [kt 13][g 8][l15 16][j 8]  (g = d/8)                 26,624 B
    // Vf: [nt 4][g 28][l15 16][j 8]  (g = s/8, l15 = d%16)     28,672 B
    // Pb: per-wave P chunk [g 4][m 16][j 8]                     4 * 1,024 B
    __shared__ short Kf[NQT * 8 * 16 * 8];
    __shared__ short Vf[4 * 28 * 16 * 8];
    __shared__ short Pb[4 * 512];

    int tid = threadIdx.x;
    int wave = tid >> 6, lane = tid & 63;
    int qq = lane >> 4, l15 = lane & 15;
    int bh = blockIdx.x;
    int b = bh >> 3, h = bh & 7;

    const short* kp = (const short*)k + (size_t)bh * T_ * D_;
    const short* vp = (const short*)v + (size_t)bh * T_ * D_;
    const short* qp = (const short*)q + (size_t)bh * T_ * D_;

    // ---- stage K ----
    for (int idx = tid; idx < 8 * 208; idx += 256) {
        int g = idx / 208, s = idx - g * 208;
        int kt = s >> 4, l = s & 15;
        bf16x8 val;
        if (s < 200) {
            val = *(const bf16x8*)&kp[s * 64 + g * 8];
        } else {
            #pragma unroll
            for (int j = 0; j < 8; ++j) val[j] = 0;
        }
        *(bf16x8*)&Kf[((kt * 8 + g) * 16 + l) * 8] = val;
    }
    // ---- stage V^T ----
    for (int idx = tid; idx < 28 * 64; idx += 256) {
        int g = idx >> 6, d = idx & 63;
        int nt = d >> 4, dl = d & 15;
        bf16x8 val;
        if (g < 25) {
            #pragma unroll
            for (int j = 0; j < 8; ++j) val[j] = vp[(g * 8 + j) * 64 + d];
        } else {
            #pragma unroll
            for (int j = 0; j < 8; ++j) val[j] = 0;
        }
        *(bf16x8*)&Vf[((nt * 28 + g) * 16 + dl) * 8] = val;
    }
    __syncthreads();

    short* pb = &Pb[wave * 512];

    for (int qt = wave; qt < NQT; qt += 4) {
        int t0 = qt * 16;
        // Q A-frags (rows t0+l15; OOB rows (>=200, last bh) read into k segment - discarded)
        bf16x8 qf[2];
        #pragma unroll
        for (int ks = 0; ks < 2; ++ks)
            qf[ks] = *(const bf16x8*)&qp[(t0 + l15) * 64 + ks * 32 + qq * 8];
        // ---- S = Q K^T ----
        f32x4 sc[NQT];
        #pragma unroll
        for (int kt = 0; kt < NQT; ++kt) {
            f32x4 a = {0.f, 0.f, 0.f, 0.f};
            bf16x8 kf0 = *(const bf16x8*)&Kf[((kt * 8 + qq) * 16 + l15) * 8];
            bf16x8 kf1 = *(const bf16x8*)&Kf[((kt * 8 + 4 + qq) * 16 + l15) * 8];
            a = __builtin_amdgcn_mfma_f32_16x16x32_bf16(qf[0], kf0, a, 0, 0, 0);
            a = __builtin_amdgcn_mfma_f32_16x16x32_bf16(qf[1], kf1, a, 0, 0, 0);
            sc[kt] = a;
        }
        // ---- scale + causal mask ----
        #pragma unroll
        for (int kt = 0; kt < NQT; ++kt) {
            #pragma unroll
            for (int r = 0; r < 4; ++r) {
                int col = kt * 16 + l15;
                int rowg = t0 + qq * 4 + r;
                sc[kt][r] = (col <= rowg) ? sc[kt][r] * SCALE : -1e30f;
            }
        }
        // ---- softmax (rows live across the 16 l15 lanes) ----
        float mx[4], sum[4], inv[4];
        #pragma unroll
        for (int r = 0; r < 4; ++r) {
            float m = -1e30f;
            #pragma unroll
            for (int kt = 0; kt < NQT; ++kt) m = fmaxf(m, sc[kt][r]);
            #pragma unroll
            for (int off = 1; off < 16; off <<= 1)
                m = fmaxf(m, __shfl_xor(m, off, 64));
            mx[r] = m;
        }
        #pragma unroll
        for (int r = 0; r < 4; ++r) sum[r] = 0.f;
        #pragma unroll
        for (int kt = 0; kt < NQT; ++kt) {
            #pragma unroll
            for (int r = 0; r < 4; ++r) {
                float e = __expf(sc[kt][r] - mx[r]);
                sc[kt][r] = e;
                sum[r] += e;
            }
        }
        #pragma unroll
        for (int r = 0; r < 4; ++r) {
            float s = sum[r];
            #pragma unroll
            for (int off = 1; off < 16; off <<= 1) s += __shfl_xor(s, off, 64);
            inv[r] = 1.0f / s;
        }
        // ---- O = P V, chunked P->LDS round-trip ----
        f32x4 oa[4] = {};
        #pragma unroll
        for (int c = 0; c < 7; ++c) {
            #pragma unroll
            for (int kt2 = 0; kt2 < 2; ++kt2) {
                int kt = c * 2 + kt2;
                int g = kt2 * 2 + (l15 >> 3);
                int jj = l15 & 7;
                #pragma unroll
                for (int r = 0; r < 4; ++r) {
                    float val = (kt < NQT) ? sc[kt][r] : 0.0f;
                    pb[(g * 16 + qq * 4 + r) * 8 + jj] = f2bf(val);
                }
            }
            bf16x8 pf = *(const bf16x8*)&pb[(qq * 16 + l15) * 8];
            #pragma unroll
            for (int nt = 0; nt < 4; ++nt) {
                bf16x8 vf = *(const bf16x8*)&Vf[((nt * 28 + c * 4 + qq) * 16 + l15) * 8];
                oa[nt] = __builtin_amdgcn_mfma_f32_16x16x32_bf16(pf, vf, oa[nt], 0, 0, 0);
            }
        }
        // ---- store O (scaled by 1/l) ----
        #pragma unroll
        for (int nt = 0; nt < 4; ++nt) {
            #pragma unroll
            for (int r = 0; r < 4; ++r) {
                int t = t0 + qq * 4 + r;
                if (t < T_) {
                    int d = nt * 16 + l15;
                    o[((size_t)b * T_ + t) * E_ + h * D_ + d] =
                        __float2bfloat16(oa[nt][r] * inv[r]);
                }
            }
        }
    }
}

extern "C" void kernel_launch(void* const* d_in, const int* in_sizes, int n_in,
                              void* d_out, int out_size, void* d_ws, size_t ws_size,
                              hipStream_t stream) {
    const float* idx    = (const float*)d_in[0];
    const float* memory = (const float*)d_in[1];
    const int* src_mask  = (const int*)d_in[2];
    const int* pred_mask = (const int*)d_in[3];
    const float* sa_wq = (const float*)d_in[4];
    const float* sa_wk = (const float*)d_in[5];
    const float* sa_wv = (const float*)d_in[6];
    const float* sa_wo = (const float*)d_in[7];
    const float* sa_bo = (const float*)d_in[8];
    const float* ca_wq = (const float*)d_in[9];
    const float* ca_wk = (const float*)d_in[10];
    const float* ca_wv = (const float*)d_in[11];
    const float* ca_wo = (const float*)d_in[12];
    const float* ca_bo = (const float*)d_in[13];
    const float* f_w1  = (const float*)d_in[14];
    const float* f_b1  = (const float*)d_in[15];
    const float* f_w2  = (const float*)d_in[16];
    const float* f_b2  = (const float*)d_in[17];
    const float* ln1_g = (const float*)d_in[18];
    const float* ln1_b = (const float*)d_in[19];
    const float* ln2_g = (const float*)d_in[20];
    const float* ln2_b = (const float*)d_in[21];
    const float* ln3_g = (const float*)d_in[22];
    const float* ln3_b = (const float*)d_in[23];
    float* out = (float*)d_out;

    const size_t BTE = (size_t)B_ * T_ * E_;    // 6,553,600 (= B*H*T*D)
    const size_t SEG = BTE;                     // one qkv segment
    const size_t EE = (size_t)E_ * E_;          // 262,144

    char* p = (char*)d_ws;
    __hip_bfloat16* qkv = (__hip_bfloat16*)p;     p += 3 * SEG * 2;   // 39.3 MB
    float* x1 = (float*)p;                        p += BTE * 4;       // 26.2 MB
    __hip_bfloat16* h_bf   = (__hip_bfloat16*)p;  p += BTE * 2;
    __hip_bfloat16* o_bf   = (__hip_bfloat16*)p;  p += BTE * 2;
    __hip_bfloat16* mem_bf = (__hip_bfloat16*)p;  p += BTE * 2;
    __hip_bfloat16* wqkv = (__hip_bfloat16*)p;    p += 3 * EE * 2;    // 1536 x 512
    __hip_bfloat16* wsao = (__hip_bfloat16*)p;    p += EE * 2;
    __hip_bfloat16* wqv2 = (__hip_bfloat16*)p;    p += 2 * EE * 2;    // 1024 x 512
    __hip_bfloat16* wcak = (__hip_bfloat16*)p;    p += EE * 2;
    __hip_bfloat16* wcao = (__hip_bfloat16*)p;    p += EE * 2;
    __hip_bfloat16* wf1  = (__hip_bfloat16*)p;    p += 4 * EE * 2;    // 2048 x 512
    __hip_bfloat16* wf2  = (__hip_bfloat16*)p;    p += 4 * EE * 2;    // 512 x 2048
    // ff intermediate (M x 2048 bf16 = 52.4 MB) aliases qkv+x1 (dead by FFN)
    __hip_bfloat16* ff_bf = (__hip_bfloat16*)qkv;

    const int M = B_ * T_;  // 12800
    dim3 blk(256);
    dim3 gqkv(12, M / 128);
    dim3 gqv2(8, M / 128);
    dim3 g512(4, M / 128);
    dim3 g2048(16, M / 128);

    // ---- fused prep ----
    PrepJobs jb;
    const float* srcs[11] = {sa_wq, sa_wk, sa_wv, sa_wo, ca_wq, ca_wv, ca_wk,
                             ca_wo, f_w1, f_w2, memory};
    __hip_bfloat16* dsts[11] = {wqkv, wqkv + EE, wqkv + 2 * EE, wsao, wqv2,
                                wqv2 + EE, wcak, wcao, wf1, wf2, mem_bf};
    int Ns[11]    = {512, 512, 512, 512, 512, 512, 512, 512, 2048, 512, 0};
    int Ks[11]    = {512, 512, 512, 512, 512, 512, 512, 512, 512, 2048, 0};
    int modes[11] = {1, 1, 1, 0, 1, 1, 1, 0, 0, 0, 2};
    int sizes[11];
    for (int i = 0; i < 10; ++i) sizes[i] = Ns[i] * Ks[i];
    sizes[10] = (int)BTE;
    jb.prefix[0] = 0;
    for (int i = 0; i < 11; ++i) {
        jb.src[i] = srcs[i]; jb.dst[i] = dsts[i];
        jb.N[i] = Ns[i]; jb.K[i] = Ks[i]; jb.mode[i] = modes[i];
        jb.prefix[i + 1] = jb.prefix[i] + sizes[i];
    }
    prep_kernel<<<8192, 256, 0, stream>>>(jb);

    // ---- self-attention block ----
    ln_kernel<<<M, 256, 0, stream>>>(idx, ln1_g, ln1_b, h_bf);
    mgemm_kernel<2,0,1,0,0,1><<<gqkv, blk, 0, stream>>>(
        (const short*)h_bf, (const short*)wqkv, nullptr, pred_mask, nullptr,
        qkv, M, 1536, E_);
    fattn_kernel<<<B_ * H_, 256, 0, stream>>>(qkv, qkv + SEG, qkv + 2 * SEG, o_bf);
    mgemm_kernel<0,0,0,1,1><<<g512, blk, 0, stream>>>(
        (const short*)o_bf, (const short*)wsao, sa_bo, nullptr, idx, x1, M, E_, E_);

    // ---- cross-attention block ----
    ln_kernel<<<M, 256, 0, stream>>>(x1, ln2_g, ln2_b, h_bf);
    mgemm_kernel<0,0,1,0,0,2><<<gqv2, blk, 0, stream>>>(
        (const short*)h_bf, (const short*)wqv2, nullptr, nullptr, nullptr,
        qkv, M, 1024, E_);   // writes q (seg 0) and v (seg 2)
    mgemm_kernel<1,0,1,0,0,1><<<g512, blk, 0, stream>>>(
        (const short*)mem_bf, (const short*)wcak, nullptr, src_mask, nullptr,
        qkv + SEG, M, E_, E_);   // writes k (seg 1 via base offset)
    fattn_kernel<<<B_ * H_, 256, 0, stream>>>(qkv, qkv + SEG, qkv + 2 * SEG, o_bf);
    mgemm_kernel<0,0,0,1,1><<<g512, blk, 0, stream>>>(
        (const short*)o_bf, (const short*)wcao, ca_bo, nullptr, x1, out, M, E_, E_);

    // ---- feed-forward block ----
    ln_kernel<<<M, 256, 0, stream>>>(out, ln3_g, ln3_b, h_bf);
    mgemm_kernel<0,1,2,0,1><<<g2048, blk, 0, stream>>>(
        (const short*)h_bf, (const short*)wf1, f_b1, nullptr, nullptr, ff_bf,
        M, 4 * E_, E_);
    mgemm_kernel<0,0,0,1,1><<<g512, blk, 0, stream>>>(
        (const short*)ff_bf, (const short*)wf2, f_b2, nullptr, out, out,
        M, E_, 4 * E_);
}